// Round 14
// baseline (231.009 us; speedup 1.0000x reference)
//
#include <hip/hip_runtime.h>
#include <hip/hip_bf16.h>

#define S_ 64
#define P_ 32
#define N_ 2048
#define H_ 64
#define E_ 64
#define D1_ 512
#define D2_ 1024
#define EPS_ 1e-5f

typedef unsigned short u16;
using bf16x8 = __attribute__((ext_vector_type(8))) __bf16;
using floatx4 = __attribute__((ext_vector_type(4))) float;

__device__ inline u16 f2bf(float x) {
    unsigned u = __float_as_uint(x);
    unsigned r = (u + 0x7fffu + ((u >> 16) & 1u)) >> 16;
    return (u16)r;
}

// ============================================================================
// Device helpers (logic verified on HW in round 9 of prior session)
// ============================================================================

// Scene prep for one (scene, d-quarter), 256 threads. Writes BN1'd A/B factors.
__device__ void prep_scene_256(int u, int tid, float* smem,
                               const float* __restrict__ pos, const float* __restrict__ h,
                               const float* __restrict__ We, const float* __restrict__ W1,
                               const float* __restrict__ g1, const float* __restrict__ be1,
                               float* __restrict__ A, float* __restrict__ Bv) {
    const int s = u >> 2, dq = u & 3;
    const int jg = tid >> 7, dl = tid & 127;   // 2 j-groups x 128 channels
    const int d = (dq << 7) + dl;
    float* hs = smem;           // 2048: h[j][e]
    float* ps = smem + 2048;    // 64: pos
    float* red = smem + 2112;   // 1024: 4 stats x 256 threads
    for (int i = tid; i < 2048; i += 256) hs[i] = h[(size_t)s * 2048 + i];
    if (tid < 64) ps[tid] = pos[s * 64 + tid];
    __syncthreads();
    float wq0 = 0.f, wq1 = 0.f;
    for (int e = 0; e < 64; ++e) {
        const float wv = W1[e * 512 + d];
        wq0 += We[e] * wv;
        wq1 += We[64 + e] * wv;
    }
    float w[16], uu[16];
#pragma unroll
    for (int jj = 0; jj < 16; ++jj) w[jj] = 0.f;
    const float4* h4 = (const float4*)hs;
    for (int e4 = 0; e4 < 16; ++e4) {
        const float c0 = W1[(64 + e4 * 4 + 0) * 512 + d];
        const float c1 = W1[(64 + e4 * 4 + 1) * 512 + d];
        const float c2 = W1[(64 + e4 * 4 + 2) * 512 + d];
        const float c3 = W1[(64 + e4 * 4 + 3) * 512 + d];
#pragma unroll
        for (int jj = 0; jj < 16; ++jj) {
            const float4 hv = h4[((jg << 4) + jj) * 16 + e4];
            w[jj] += hv.x * c0 + hv.y * c1 + hv.z * c2 + hv.w * c3;
        }
    }
    float sw = 0.f, sww = 0.f, su = 0.f, suu = 0.f;
#pragma unroll
    for (int jj = 0; jj < 16; ++jj) {
        const int j = (jg << 4) + jj;
        uu[jj] = ps[2 * j] * wq0 + ps[2 * j + 1] * wq1;
        w[jj] += uu[jj];
        sw += w[jj]; sww += w[jj] * w[jj];
        su += uu[jj]; suu += uu[jj] * uu[jj];
    }
    red[(jg << 7) + dl] = sw;
    red[256 + (jg << 7) + dl] = sww;
    red[512 + (jg << 7) + dl] = su;
    red[768 + (jg << 7) + dl] = suu;
    __syncthreads();
    const float tw = red[dl] + red[128 + dl];
    const float tww = red[256 + dl] + red[384 + dl];
    const float tu = red[512 + dl] + red[640 + dl];
    const float tuu = red[768 + dl] + red[896 + dl];
    const float mw = tw * (1.f / 32.f), mu2 = tu * (1.f / 32.f);
    const float var = (tww * (1.f / 32.f) - mw * mw) + (tuu * (1.f / 32.f) - mu2 * mu2);
    const float sc = rsqrtf(var + EPS_) * g1[d];
    const float bb = be1[d];
#pragma unroll
    for (int jj = 0; jj < 16; ++jj) {
        const int j = (jg << 4) + jj;
        A[(size_t)(s * 32 + j) * 512 + d] = (w[jj] - mw) * sc + bb;
        Bv[(size_t)(s * 32 + j) * 512 + d] = (uu[jj] - mu2) * sc;
    }
}

// W2 transpose+bf16 for one 64x64 tile, 256 threads.
__device__ void w2t_tile_256(int b2, int tid, void* smem,
                             const float* __restrict__ W2, u16* __restrict__ w2t) {
    float (*tile)[65] = (float (*)[65])smem;  // 16.6 KB
    const int bi = b2 & 15, bj = b2 >> 4;     // 16 n-tiles x 8 k-tiles
    const int tx = tid & 63, ty = tid >> 6;   // 64 x 4
#pragma unroll
    for (int i = 0; i < 64; i += 4)
        tile[ty + i][tx] = W2[(size_t)(bj * 64 + ty + i) * 1024 + bi * 64 + tx];
    __syncthreads();
#pragma unroll
    for (int i = 0; i < 64; i += 4)
        w2t[(size_t)(bi * 64 + ty + i) * 512 + bj * 64 + tx] = f2bf(tile[tx][ty + i]);
}

// ============================================================================
// Fused GEMM + BN2 finalize, round-14: block = (scene, 128-col slice) so the
// BN2 statistic (mean/var over all P*P = 1024 rows per col) CLOSES inside the
// block -> k_final eliminated with NO cross-block communication (no fences
// [r11 disaster], no cooperative launch [r12 broken]). Grid 512 x 256 thr,
// 52 KB static LDS -> 2 blocks/CU resident (the r13-proven 2-domain config).
// Inner K-loop = r13 verbatim shape: wave-tile 64x128, af[4]/wf[8] (2.67
// MFMA/read), single-buffered Ws via global_load_lds, __syncthreads drains,
// R5 swizzles. Scene's 1024 rows processed as 4 chunks of 256 (8 peds):
//   per chunk: K-loop (8 tiles) -> epilogue: single-ext (sign(g2), verified
//   r11/r13) to global + wsum/wsq accumulated in REGISTERS across chunks.
// After chunks: 4 KB LDS wave-reduce -> inline BN2 finalize -> out.
// ext re-read is the block's OWN writes (same CU/L2): threadfence_block only.
// Cost accepted: As-build runs 2x total (8 col-splits vs r13's 4); Ws staging
// halves. k_prep unchanged.
// ============================================================================
__global__ __launch_bounds__(256, 2)
void k_gemm(const float* __restrict__ A, const float* __restrict__ Bv,
            const u16* __restrict__ w2t, const float* __restrict__ g2,
            const float* __restrict__ be2,
            float* __restrict__ ext, float* __restrict__ out) {
    __shared__ __align__(16) u16 As[256 * 64];    // 32 KB (256 rows = 8 peds x 32 j)
    __shared__ __align__(16) u16 Ws[128 * 64];    // 16 KB (128 cols x 64 k)
    __shared__ float red_s[4][128];               // 2 KB  (per-wave col sums)
    __shared__ float red_q[4][128];               // 2 KB
    const int tid = threadIdx.x;
    const int wave = tid >> 6, lane = tid & 63;   // 4 waves: wm = wave (0..3)
    const int quad = lane >> 4, l16 = lane & 15;
    const int lrow = lane >> 3, lchk = lane & 7;
    const int gchk = lchk ^ lrow;
    const int sj = tid >> 3, sc8 = tid & 7;       // j-row 0..31, k-oct 0..7
    const int bid = blockIdx.x;
    const int s = bid >> 3, cs = bid & 7;         // scene, 128-col slice
    const int N0 = cs << 7;
    const float* Aj = A + ((size_t)(s * 32 + sj) << 9) + (sc8 << 3);
    const int swz = (sc8 ^ (sj & 7)) << 3;

    float wsum_t[8] = {}, wsq_t[8] = {};          // per-thread BN2 partials

    for (int c = 0; c < 4; ++c) {                 // M-chunk: peds c*8 .. c*8+8
        const float* Bp = Bv + ((size_t)(s * 32 + c * 8) << 9) + (sc8 << 3);
        floatx4 acc[4][8] = {};
        for (int it = 0; it < 8; ++it) {
            const int k0 = it << 6;
            // stage Ws: 128 rows x 64 k via global_load_lds (4 per wave)
#pragma unroll
            for (int t = 0; t < 4; ++t) {
                const int rbase = (wave << 5) + (t << 3);
                const u16* gb = w2t + (size_t)(N0 + rbase + lrow) * 512 + (k0 + (gchk << 3));
                __builtin_amdgcn_global_load_lds(
                    (const __attribute__((address_space(1))) void*)gb,
                    (__attribute__((address_space(3))) void*)(Ws + (rbase << 6)), 16, 0, 0);
            }
            // build As: 256 rows (8 peds x 32 j) x 64 k, per-lane relu-diff
            {
                const float4 alo = *(const float4*)(Aj + k0);
                const float4 ahi = *(const float4*)(Aj + k0 + 4);
#pragma unroll
                for (int p = 0; p < 8; ++p) {
                    const int r = (p << 5) + sj;
                    const float4 blo = *(const float4*)(Bp + ((size_t)p << 9) + k0);
                    const float4 bhi = *(const float4*)(Bp + ((size_t)p << 9) + k0 + 4);
                    bf16x8 o;
                    o[0] = (__bf16)fmaxf(alo.x - blo.x, 0.f);
                    o[1] = (__bf16)fmaxf(alo.y - blo.y, 0.f);
                    o[2] = (__bf16)fmaxf(alo.z - blo.z, 0.f);
                    o[3] = (__bf16)fmaxf(alo.w - blo.w, 0.f);
                    o[4] = (__bf16)fmaxf(ahi.x - bhi.x, 0.f);
                    o[5] = (__bf16)fmaxf(ahi.y - bhi.y, 0.f);
                    o[6] = (__bf16)fmaxf(ahi.z - bhi.z, 0.f);
                    o[7] = (__bf16)fmaxf(ahi.w - bhi.w, 0.f);
                    *(bf16x8*)(As + (r << 6) + swz) = o;
                }
            }
            __syncthreads();
            // MFMA: 64 per wave per K-tile (wave-tile 64 rows x 128 cols)
#pragma unroll
            for (int kk = 0; kk < 2; ++kk) {
                const int ck = (kk << 2) + quad;
                const int po = (ck ^ (l16 & 7)) << 3;
                bf16x8 af[4], wf[8];
#pragma unroll
                for (int tm = 0; tm < 4; ++tm) {
                    const int row = (wave << 6) + (tm << 4) + l16;
                    af[tm] = *(const bf16x8*)(As + (row << 6) + po);
                }
#pragma unroll
                for (int tn = 0; tn < 8; ++tn) {
                    const int wrow = (tn << 4) + l16;
                    wf[tn] = *(const bf16x8*)(Ws + (wrow << 6) + ((ck ^ (wrow & 7)) << 3));
                }
#pragma unroll
                for (int tm = 0; tm < 4; ++tm)
#pragma unroll
                    for (int tn = 0; tn < 8; ++tn)
                        acc[tm][tn] = __builtin_amdgcn_mfma_f32_16x16x32_bf16(
                            af[tm], wf[tn], acc[tm][tn], 0, 0, 0);
            }
            __syncthreads();
        }
        // chunk epilogue: single j-extreme per ped + BN2 register partials
#pragma unroll
        for (int tn = 0; tn < 8; ++tn) {
            const int colb = (tn << 4) + l16;
            const float g2v = g2[N0 + colb];
#pragma unroll
            for (int gp = 0; gp < 2; ++gp) {
                float vmax = -3.4e38f, vmin = 3.4e38f, vs = 0.f, vq = 0.f;
#pragma unroll
                for (int tm = gp * 2; tm < gp * 2 + 2; ++tm)
#pragma unroll
                    for (int r = 0; r < 4; ++r) {
                        const float v = acc[tm][tn][r];
                        vmax = fmaxf(vmax, v);
                        vmin = fminf(vmin, v);
                        vs += v;
                        vq += v * v;
                    }
#pragma unroll
                for (int off = 16; off < 64; off <<= 1) {
                    vmax = fmaxf(vmax, __shfl_xor(vmax, off));
                    vmin = fminf(vmin, __shfl_xor(vmin, off));
                    vs += __shfl_xor(vs, off);
                    vq += __shfl_xor(vq, off);
                }
                if (quad == 0) {
                    const int kg = s * 32 + c * 8 + wave * 2 + gp;
                    ext[(size_t)kg * 1024 + N0 + colb] = (g2v >= 0.f) ? vmax : vmin;
                }
                wsum_t[tn] += vs;
                wsq_t[tn] += vq;
            }
        }
    }

    // ---- in-block BN2 finalize (replaces k_final; own-writes re-read) ----
    if (quad == 0) {
#pragma unroll
        for (int tn = 0; tn < 8; ++tn) {
            red_s[wave][(tn << 4) + l16] = wsum_t[tn];
            red_q[wave][(tn << 4) + l16] = wsq_t[tn];
        }
    }
    __threadfence_block();   // drain this block's ext stores to L2
    __syncthreads();
    {
        const int colb = tid & 127, kh = tid >> 7;  // col, ped-half
        const float sm = red_s[0][colb] + red_s[1][colb] + red_s[2][colb] + red_s[3][colb];
        const float sq = red_q[0][colb] + red_q[1][colb] + red_q[2][colb] + red_q[3][colb];
        const float mu = sm * (1.f / 1024.f);
        const float var = sq * (1.f / 1024.f) - mu * mu;
        const float scale = g2[N0 + colb] * rsqrtf(var + EPS_);
        const float bb = be2[N0 + colb];
#pragma unroll
        for (int kq = 0; kq < 16; ++kq) {
            const int k = (kh << 4) + kq;
            const float v = ext[(size_t)(s * 32 + k) * 1024 + N0 + colb];
            out[(size_t)(s * 32 + k) * 1024 + N0 + colb] =
                fmaxf((v - mu) * scale + bb, 0.f);
        }
    }
}

// ============================================================================
// Prep kernel (unchanged)
// ============================================================================
__global__ __launch_bounds__(256)
void k_prep(const float* __restrict__ pos, const float* __restrict__ h,
            const float* __restrict__ We, const float* __restrict__ W1,
            const float* __restrict__ g1, const float* __restrict__ be1,
            const float* __restrict__ W2,
            float* __restrict__ A, float* __restrict__ Bv, u16* __restrict__ w2t) {
    __shared__ __align__(16) char smem_raw[16912];
    const int bid = blockIdx.x;
    if (bid < 256)
        prep_scene_256(bid, threadIdx.x, (float*)smem_raw, pos, h, We, W1, g1, be1, A, Bv);
    else
        w2t_tile_256(bid - 256, threadIdx.x, smem_raw, W2, w2t);
}

extern "C" void kernel_launch(void* const* d_in, const int* in_sizes, int n_in,
                              void* d_out, int out_size, void* d_ws, size_t ws_size,
                              hipStream_t stream) {
    const float* h_states = (const float*)d_in[0];
    const float* end_pos = (const float*)d_in[2];
    const float* W_embed = (const float*)d_in[4];
    const float* W1 = (const float*)d_in[6];
    const float* g1 = (const float*)d_in[8];
    const float* be1 = (const float*)d_in[9];
    const float* W2 = (const float*)d_in[10];
    const float* g2 = (const float*)d_in[12];
    const float* be2 = (const float*)d_in[13];
    float* out = (float*)d_out;

    float* Abuf = (float*)d_ws;                // 1,048,576 f
    float* Bbuf = Abuf + 1048576;              // 1,048,576 f
    float* ext = Bbuf + 1048576;               // 2,097,152 f
    u16* w2t = (u16*)(ext + 2097152);          // 524,288 u16

    k_prep<<<dim3(384), dim3(256), 0, stream>>>(end_pos, h_states, W_embed, W1,
                                                g1, be1, W2, Abuf, Bbuf, w2t);
    k_gemm<<<dim3(512), dim3(256), 0, stream>>>(Abuf, Bbuf, w2t, g2, be2, ext, out);
}

// Round 16
// 190.641 us; speedup vs baseline: 1.2118x; 1.2118x over previous
//
#include <hip/hip_runtime.h>
#include <hip/hip_bf16.h>

#define S_ 64
#define P_ 32
#define N_ 2048
#define H_ 64
#define E_ 64
#define D1_ 512
#define D2_ 1024
#define EPS_ 1e-5f

typedef unsigned short u16;
using bf16x8 = __attribute__((ext_vector_type(8))) __bf16;
using floatx4 = __attribute__((ext_vector_type(4))) float;

__device__ inline u16 f2bf(float x) {
    unsigned u = __float_as_uint(x);
    unsigned r = (u + 0x7fffu + ((u >> 16) & 1u)) >> 16;
    return (u16)r;
}

// ============================================================================
// Device helpers (logic verified on HW in round 9 of prior session)
// ============================================================================

// Scene prep for one (scene, d-quarter), 256 threads. Writes BN1'd A/B factors.
__device__ void prep_scene_256(int u, int tid, float* smem,
                               const float* __restrict__ pos, const float* __restrict__ h,
                               const float* __restrict__ We, const float* __restrict__ W1,
                               const float* __restrict__ g1, const float* __restrict__ be1,
                               float* __restrict__ A, float* __restrict__ Bv) {
    const int s = u >> 2, dq = u & 3;
    const int jg = tid >> 7, dl = tid & 127;   // 2 j-groups x 128 channels
    const int d = (dq << 7) + dl;
    float* hs = smem;           // 2048: h[j][e]
    float* ps = smem + 2048;    // 64: pos
    float* red = smem + 2112;   // 1024: 4 stats x 256 threads
    for (int i = tid; i < 2048; i += 256) hs[i] = h[(size_t)s * 2048 + i];
    if (tid < 64) ps[tid] = pos[s * 64 + tid];
    __syncthreads();
    float wq0 = 0.f, wq1 = 0.f;
    for (int e = 0; e < 64; ++e) {
        const float wv = W1[e * 512 + d];
        wq0 += We[e] * wv;
        wq1 += We[64 + e] * wv;
    }
    float w[16], uu[16];
#pragma unroll
    for (int jj = 0; jj < 16; ++jj) w[jj] = 0.f;
    const float4* h4 = (const float4*)hs;
    for (int e4 = 0; e4 < 16; ++e4) {
        const float c0 = W1[(64 + e4 * 4 + 0) * 512 + d];
        const float c1 = W1[(64 + e4 * 4 + 1) * 512 + d];
        const float c2 = W1[(64 + e4 * 4 + 2) * 512 + d];
        const float c3 = W1[(64 + e4 * 4 + 3) * 512 + d];
#pragma unroll
        for (int jj = 0; jj < 16; ++jj) {
            const float4 hv = h4[((jg << 4) + jj) * 16 + e4];
            w[jj] += hv.x * c0 + hv.y * c1 + hv.z * c2 + hv.w * c3;
        }
    }
    float sw = 0.f, sww = 0.f, su = 0.f, suu = 0.f;
#pragma unroll
    for (int jj = 0; jj < 16; ++jj) {
        const int j = (jg << 4) + jj;
        uu[jj] = ps[2 * j] * wq0 + ps[2 * j + 1] * wq1;
        w[jj] += uu[jj];
        sw += w[jj]; sww += w[jj] * w[jj];
        su += uu[jj]; suu += uu[jj] * uu[jj];
    }
    red[(jg << 7) + dl] = sw;
    red[256 + (jg << 7) + dl] = sww;
    red[512 + (jg << 7) + dl] = su;
    red[768 + (jg << 7) + dl] = suu;
    __syncthreads();
    const float tw = red[dl] + red[128 + dl];
    const float tww = red[256 + dl] + red[384 + dl];
    const float tu = red[512 + dl] + red[640 + dl];
    const float tuu = red[768 + dl] + red[896 + dl];
    const float mw = tw * (1.f / 32.f), mu2 = tu * (1.f / 32.f);
    const float var = (tww * (1.f / 32.f) - mw * mw) + (tuu * (1.f / 32.f) - mu2 * mu2);
    const float sc = rsqrtf(var + EPS_) * g1[d];
    const float bb = be1[d];
#pragma unroll
    for (int jj = 0; jj < 16; ++jj) {
        const int j = (jg << 4) + jj;
        A[(size_t)(s * 32 + j) * 512 + d] = (w[jj] - mw) * sc + bb;
        Bv[(size_t)(s * 32 + j) * 512 + d] = (uu[jj] - mu2) * sc;
    }
}

// W2 transpose+bf16 for one 64x64 tile, 256 threads.
__device__ void w2t_tile_256(int b2, int tid, void* smem,
                             const float* __restrict__ W2, u16* __restrict__ w2t) {
    float (*tile)[65] = (float (*)[65])smem;  // 16.6 KB
    const int bi = b2 & 15, bj = b2 >> 4;     // 16 n-tiles x 8 k-tiles
    const int tx = tid & 63, ty = tid >> 6;   // 64 x 4
#pragma unroll
    for (int i = 0; i < 64; i += 4)
        tile[ty + i][tx] = W2[(size_t)(bj * 64 + ty + i) * 1024 + bi * 64 + tx];
    __syncthreads();
#pragma unroll
    for (int i = 0; i < 64; i += 4)
        w2t[(size_t)(bi * 64 + ty + i) * 512 + bj * 64 + tx] = f2bf(tile[tx][ty + i]);
}

#define LGKM0() asm volatile("s_waitcnt lgkmcnt(0)" ::: "memory")
#define VMC10() asm volatile("s_waitcnt vmcnt(10)" ::: "memory")
#define VM0()   asm volatile("s_waitcnt vmcnt(0)" ::: "memory")
#define SCHED_FENCE() __builtin_amdgcn_sched_barrier(0)

// ============================================================================
// Fused GEMM: r13 geometry VERBATIM (48 KB static LDS, 2-3 blocks/CU, block =
// (M-tile 128 rows, 256-col split), grid 2048, wave-tile 64x128 af[4]/wf[8],
// R5 swizzles, single-buffered Ws) + counted-drain raw barrier + A/Bv register
// prefetch. ROUND-16 FIX of r15's race (rule #18, compile-time reordering):
//   fence A (top of body): next-iter ds_writes can't hoist above tail barrier
//   fence B (stage->LOADR): pins gld-before-LOADR so vmcnt(10) counts exactly
//     the 8 gld (LOADR reads restrict-disjoint A/Bv, was free to hoist)
//   fence C (after head barrier): post-barrier ds_reads can't hoist above
//     s_barrier (raw s_barrier is NOT a compile-time memory fence)
// Per tile: build As from regs(it) -> stage Ws(it) [8 gld] -> LOADR(it+1)
// [10 loads] -> vmcnt(10) -> lgkmcnt(0) -> s_barrier -> 24 ds_read + 64 MFMA
// -> s_barrier. Single-ext epilogue (sign(g2)) verified r11/r13.
// ============================================================================
__global__ __launch_bounds__(256, 2)
void k_gemm(const float* __restrict__ A, const float* __restrict__ Bv,
            const u16* __restrict__ w2t, const float* __restrict__ g2,
            float* __restrict__ ext,
            float* __restrict__ psum, float* __restrict__ psumsq) {
    __shared__ __align__(16) u16 As[128 * 64];   // 16 KB
    __shared__ __align__(16) u16 Ws[256 * 64];   // 32 KB
    const int tid = threadIdx.x;
    const int bid = blockIdx.x;
    const int wave = tid >> 6, lane = tid & 63;
    const int wm = wave >> 1, wn = wave & 1;
    const int quad = lane >> 4, l16 = lane & 15;
    const int lrow = lane >> 3, lchk = lane & 7;
    const int gchk = lchk ^ lrow;
    const int sj = tid >> 3, sc8 = tid & 7;
    const int mt = bid >> 2, cs = bid & 3;       // consecutive bids: same M-tile
    const int s2 = mt >> 3, rb = mt & 7;
    const int pedb = rb << 2;
    const int N0 = cs << 8;
    const float* Aj = A + ((size_t)(s2 * 32 + sj) << 9) + (sc8 << 3);
    const float* Bp = Bv + ((size_t)(s2 * 32 + pedb) << 9) + (sc8 << 3);
    const int swz = (sc8 ^ (sj & 7)) << 3;

    float4 ra0, ra1, rb0[4], rb1[4];   // prefetched A/B sources (static idx)
    floatx4 acc[4][8] = {};

#define LOADR(KX)                                                              \
    do {                                                                       \
        ra0 = *(const float4*)(Aj + (KX));                                     \
        ra1 = *(const float4*)(Aj + (KX) + 4);                                 \
        _Pragma("unroll")                                                      \
        for (int p = 0; p < 4; ++p) {                                          \
            rb0[p] = *(const float4*)(Bp + ((size_t)p << 9) + (KX));           \
            rb1[p] = *(const float4*)(Bp + ((size_t)p << 9) + (KX) + 4);       \
        }                                                                      \
    } while (0)

#define BUILDA()                                                               \
    do {                                                                       \
        _Pragma("unroll")                                                      \
        for (int p = 0; p < 4; ++p) {                                          \
            const int r = (p << 5) + sj;                                       \
            bf16x8 o;                                                          \
            o[0] = (__bf16)fmaxf(ra0.x - rb0[p].x, 0.f);                       \
            o[1] = (__bf16)fmaxf(ra0.y - rb0[p].y, 0.f);                       \
            o[2] = (__bf16)fmaxf(ra0.z - rb0[p].z, 0.f);                       \
            o[3] = (__bf16)fmaxf(ra0.w - rb0[p].w, 0.f);                       \
            o[4] = (__bf16)fmaxf(ra1.x - rb1[p].x, 0.f);                       \
            o[5] = (__bf16)fmaxf(ra1.y - rb1[p].y, 0.f);                       \
            o[6] = (__bf16)fmaxf(ra1.z - rb1[p].z, 0.f);                       \
            o[7] = (__bf16)fmaxf(ra1.w - rb1[p].w, 0.f);                       \
            *(bf16x8*)(As + (r << 6) + swz) = o;                               \
        }                                                                      \
    } while (0)

    // ---- prologue: load regs(0) ----
    LOADR(0);

    for (int it = 0; it < 8; ++it) {
        const int k0 = it << 6;
        SCHED_FENCE();    // fence A: nothing crosses the preceding tail barrier
        // build As(it) from prefetched regs (VALU + ds_write only)
        BUILDA();
        // stage Ws(it): 256 rows x 64 k via global_load_lds (8 per thread)
#pragma unroll
        for (int t = 0; t < 8; ++t) {
            const int rbase = (wave << 6) + (t << 3);
            const u16* gb = w2t + (size_t)(N0 + rbase + lrow) * 512 + (k0 + (gchk << 3));
            __builtin_amdgcn_global_load_lds(
                (const __attribute__((address_space(1))) void*)gb,
                (__attribute__((address_space(3))) void*)(Ws + (rbase << 6)), 16, 0, 0);
        }
        SCHED_FENCE();    // fence B: all 8 gld issued before LOADR's 10 loads
        // prefetch regs(it+1); counted drain: 8 gld retired, 10 loads fly
        if (it < 7) {
            LOADR(k0 + 64);
            VMC10();
        } else {
            VM0();
        }
        LGKM0();          // As ds_writes retired
        __builtin_amdgcn_s_barrier();
        SCHED_FENCE();    // fence C: ds_reads may not hoist above the barrier
#pragma unroll
        for (int kk = 0; kk < 2; ++kk) {
            const int ck = (kk << 2) + quad;
            const int po = (ck ^ (l16 & 7)) << 3;
            bf16x8 af[4], wf[8];
#pragma unroll
            for (int tm = 0; tm < 4; ++tm) {
                const int row = (wm << 6) + (tm << 4) + l16;
                af[tm] = *(const bf16x8*)(As + (row << 6) + po);
            }
#pragma unroll
            for (int tn = 0; tn < 8; ++tn) {
                const int wrow = (wn << 7) + (tn << 4) + l16;
                wf[tn] = *(const bf16x8*)(Ws + (wrow << 6) + ((ck ^ (wrow & 7)) << 3));
            }
#pragma unroll
            for (int tm = 0; tm < 4; ++tm)
#pragma unroll
                for (int tn = 0; tn < 8; ++tn)
                    acc[tm][tn] = __builtin_amdgcn_mfma_f32_16x16x32_bf16(
                        af[tm], wf[tn], acc[tm][tn], 0, 0, 0);
        }
        // tail barrier: each wave's LDS reads retired before its MFMAs issue,
        // so arrival implies reads done; fence A (next iter) pins the writes.
        __builtin_amdgcn_s_barrier();
    }
#undef LOADR
#undef BUILDA

    // epilogue: single j-extreme per ped (sign(g2)-selected) + BN2 partials
#pragma unroll
    for (int tn = 0; tn < 8; ++tn) {
        const int col = N0 + (wn << 7) + (tn << 4) + l16;
        const float g2v = g2[col];
        float wsum = 0.f, wsq = 0.f;
#pragma unroll
        for (int gp = 0; gp < 2; ++gp) {
            float vmax = -3.4e38f, vmin = 3.4e38f, vs = 0.f, vq = 0.f;
#pragma unroll
            for (int tm = gp * 2; tm < gp * 2 + 2; ++tm)
#pragma unroll
                for (int r = 0; r < 4; ++r) {
                    const float v = acc[tm][tn][r];
                    vmax = fmaxf(vmax, v);
                    vmin = fminf(vmin, v);
                    vs += v;
                    vq += v * v;
                }
#pragma unroll
            for (int off = 16; off < 64; off <<= 1) {
                vmax = fmaxf(vmax, __shfl_xor(vmax, off));
                vmin = fminf(vmin, __shfl_xor(vmin, off));
                vs += __shfl_xor(vs, off);
                vq += __shfl_xor(vq, off);
            }
            if (quad == 0) {
                const int kg = s2 * 32 + pedb + (wm << 1) + gp;
                ext[(size_t)kg * 1024 + col] = (g2v >= 0.f) ? vmax : vmin;
            }
            wsum += vs;
            wsq += vq;
        }
        if (quad == 0) {
            const int slot = (s2 << 4) + (rb << 1) + wm;  // 16 per scene
            psum[(size_t)slot * 1024 + col] = wsum;
            psumsq[(size_t)slot * 1024 + col] = wsq;
        }
    }
}

// ============================================================================
// Prep / final kernels (r13 verbatim)
// ============================================================================
__global__ __launch_bounds__(256)
void k_prep(const float* __restrict__ pos, const float* __restrict__ h,
            const float* __restrict__ We, const float* __restrict__ W1,
            const float* __restrict__ g1, const float* __restrict__ be1,
            const float* __restrict__ W2,
            float* __restrict__ A, float* __restrict__ Bv, u16* __restrict__ w2t) {
    __shared__ __align__(16) char smem_raw[16912];
    const int bid = blockIdx.x;
    if (bid < 256)
        prep_scene_256(bid, threadIdx.x, (float*)smem_raw, pos, h, We, W1, g1, be1, A, Bv);
    else
        w2t_tile_256(bid - 256, threadIdx.x, smem_raw, W2, w2t);
}

__global__ __launch_bounds__(256)
void k_final(const float* __restrict__ ext,
             const float* __restrict__ psum, const float* __restrict__ psumsq,
             const float* __restrict__ g2, const float* __restrict__ be2,
             float* __restrict__ out) {
    const int u = blockIdx.x, tid = threadIdx.x;
    const int s3 = u >> 2;
    const int c = ((u & 3) << 8) + tid;
    float sm = 0.f, sq = 0.f;
#pragma unroll
    for (int t = 0; t < 16; ++t) {
        sm += psum[(size_t)(s3 * 16 + t) * 1024 + c];
        sq += psumsq[(size_t)(s3 * 16 + t) * 1024 + c];
    }
    const float mu = sm * (1.f / 1024.f);
    const float var = sq * (1.f / 1024.f) - mu * mu;
    const float inv = rsqrtf(var + EPS_);
    const float scale = g2[c] * inv;
    const float bb = be2[c];
    for (int k = 0; k < 32; ++k) {
        const float v = ext[(size_t)(s3 * 32 + k) * 1024 + c];
        out[(size_t)(s3 * 32 + k) * 1024 + c] = fmaxf((v - mu) * scale + bb, 0.f);
    }
}

extern "C" void kernel_launch(void* const* d_in, const int* in_sizes, int n_in,
                              void* d_out, int out_size, void* d_ws, size_t ws_size,
                              hipStream_t stream) {
    const float* h_states = (const float*)d_in[0];
    const float* end_pos = (const float*)d_in[2];
    const float* W_embed = (const float*)d_in[4];
    const float* W1 = (const float*)d_in[6];
    const float* g1 = (const float*)d_in[8];
    const float* be1 = (const float*)d_in[9];
    const float* W2 = (const float*)d_in[10];
    const float* g2 = (const float*)d_in[12];
    const float* be2 = (const float*)d_in[13];
    float* out = (float*)d_out;

    float* Abuf = (float*)d_ws;                // 1,048,576 f
    float* Bbuf = Abuf + 1048576;              // 1,048,576 f
    float* ext = Bbuf + 1048576;               // 2,097,152 f
    float* psum = ext + 2097152;               // 1,048,576 f
    float* psumsq = psum + 1048576;            // 1,048,576 f
    u16* w2t = (u16*)(psumsq + 1048576);       // 524,288 u16

    k_prep<<<dim3(384), dim3(256), 0, stream>>>(end_pos, h_states, W_embed, W1,
                                                g1, be1, W2, Abuf, Bbuf, w2t);
    k_gemm<<<dim3(2048), dim3(256), 0, stream>>>(Abuf, Bbuf, w2t, g2,
                                                 ext, psum, psumsq);
    k_final<<<dim3(256), dim3(256), 0, stream>>>(ext, psum, psumsq, g2, be2, out);
}

// Round 17
// 182.139 us; speedup vs baseline: 1.2683x; 1.0467x over previous
//
#include <hip/hip_runtime.h>
#include <hip/hip_bf16.h>

#define S_ 64
#define P_ 32
#define N_ 2048
#define H_ 64
#define E_ 64
#define D1_ 512
#define D2_ 1024
#define EPS_ 1e-5f

typedef unsigned short u16;
using bf16x8 = __attribute__((ext_vector_type(8))) __bf16;
using floatx4 = __attribute__((ext_vector_type(4))) float;

__device__ inline u16 f2bf(float x) {
    unsigned u = __float_as_uint(x);
    unsigned r = (u + 0x7fffu + ((u >> 16) & 1u)) >> 16;
    return (u16)r;
}

// ============================================================================
// Device helpers (logic verified on HW across this + prior session)
// ============================================================================

// Scene prep for one (scene, d-quarter), 256 threads. Writes BN1'd A/B factors.
__device__ void prep_scene_256(int u, int tid, float* smem,
                               const float* __restrict__ pos, const float* __restrict__ h,
                               const float* __restrict__ We, const float* __restrict__ W1,
                               const float* __restrict__ g1, const float* __restrict__ be1,
                               float* __restrict__ A, float* __restrict__ Bv) {
    const int s = u >> 2, dq = u & 3;
    const int jg = tid >> 7, dl = tid & 127;   // 2 j-groups x 128 channels
    const int d = (dq << 7) + dl;
    float* hs = smem;           // 2048: h[j][e]
    float* ps = smem + 2048;    // 64: pos
    float* red = smem + 2112;   // 1024: 4 stats x 256 threads
    for (int i = tid; i < 2048; i += 256) hs[i] = h[(size_t)s * 2048 + i];
    if (tid < 64) ps[tid] = pos[s * 64 + tid];
    __syncthreads();
    float wq0 = 0.f, wq1 = 0.f;
    for (int e = 0; e < 64; ++e) {
        const float wv = W1[e * 512 + d];
        wq0 += We[e] * wv;
        wq1 += We[64 + e] * wv;
    }
    float w[16], uu[16];
#pragma unroll
    for (int jj = 0; jj < 16; ++jj) w[jj] = 0.f;
    const float4* h4 = (const float4*)hs;
    for (int e4 = 0; e4 < 16; ++e4) {
        const float c0 = W1[(64 + e4 * 4 + 0) * 512 + d];
        const float c1 = W1[(64 + e4 * 4 + 1) * 512 + d];
        const float c2 = W1[(64 + e4 * 4 + 2) * 512 + d];
        const float c3 = W1[(64 + e4 * 4 + 3) * 512 + d];
#pragma unroll
        for (int jj = 0; jj < 16; ++jj) {
            const float4 hv = h4[((jg << 4) + jj) * 16 + e4];
            w[jj] += hv.x * c0 + hv.y * c1 + hv.z * c2 + hv.w * c3;
        }
    }
    float sw = 0.f, sww = 0.f, su = 0.f, suu = 0.f;
#pragma unroll
    for (int jj = 0; jj < 16; ++jj) {
        const int j = (jg << 4) + jj;
        uu[jj] = ps[2 * j] * wq0 + ps[2 * j + 1] * wq1;
        w[jj] += uu[jj];
        sw += w[jj]; sww += w[jj] * w[jj];
        su += uu[jj]; suu += uu[jj] * uu[jj];
    }
    red[(jg << 7) + dl] = sw;
    red[256 + (jg << 7) + dl] = sww;
    red[512 + (jg << 7) + dl] = su;
    red[768 + (jg << 7) + dl] = suu;
    __syncthreads();
    const float tw = red[dl] + red[128 + dl];
    const float tww = red[256 + dl] + red[384 + dl];
    const float tu = red[512 + dl] + red[640 + dl];
    const float tuu = red[768 + dl] + red[896 + dl];
    const float mw = tw * (1.f / 32.f), mu2 = tu * (1.f / 32.f);
    const float var = (tww * (1.f / 32.f) - mw * mw) + (tuu * (1.f / 32.f) - mu2 * mu2);
    const float sc = rsqrtf(var + EPS_) * g1[d];
    const float bb = be1[d];
#pragma unroll
    for (int jj = 0; jj < 16; ++jj) {
        const int j = (jg << 4) + jj;
        A[(size_t)(s * 32 + j) * 512 + d] = (w[jj] - mw) * sc + bb;
        Bv[(size_t)(s * 32 + j) * 512 + d] = (uu[jj] - mu2) * sc;
    }
}

// W2 transpose+bf16 for one 64x64 tile, 256 threads.
__device__ void w2t_tile_256(int b2, int tid, void* smem,
                             const float* __restrict__ W2, u16* __restrict__ w2t) {
    float (*tile)[65] = (float (*)[65])smem;  // 16.6 KB
    const int bi = b2 & 15, bj = b2 >> 4;     // 16 n-tiles x 8 k-tiles
    const int tx = tid & 63, ty = tid >> 6;   // 64 x 4
#pragma unroll
    for (int i = 0; i < 64; i += 4)
        tile[ty + i][tx] = W2[(size_t)(bj * 64 + ty + i) * 1024 + bi * 64 + tx];
    __syncthreads();
#pragma unroll
    for (int i = 0; i < 64; i += 4)
        w2t[(size_t)(bi * 64 + ty + i) * 512 + bj * 64 + tx] = f2bf(tile[tx][ty + i]);
}

// ============================================================================
// Fused GEMM — FINAL configuration (session empirical optimum):
// r8's proven loop: 48 KB static LDS, 2-3 blocks/CU (independent barrier
// domains = the only structure that beat all pipelined variants across 16
// rounds), block = (M-tile 128 rows, 256-col split), grid 2048 (consecutive
// bids share the M-tile for L2 reuse), wave-tile 64x128 af[4]/wf[8] (2.67
// MFMA/read, volume-optimal for 128-VGPR acc), single-buffered Ws via
// global_load_lds, __syncthreads drains (counted-vmcnt variants measured
// SLOWER at this residency: r16 100.4 vs 91.1), R5 swizzles, 0 bank conflicts.
// Epilogue: single j-extreme keyed on sign(g2) (verified r11/r13; WRITE
// 24.6 -> 16.4 MB). Falsified levers (do not revisit): 4/2-phase 256² pipes,
// vmcnt-counted drains at 48/80/96 KB, 1-block full dbuf, >=3-block TLP,
// stagger, setprio, per-block fences, cooperative fusion, BN2-in-block.
// ============================================================================
__global__ __launch_bounds__(256, 2)
void k_gemm(const float* __restrict__ A, const float* __restrict__ Bv,
            const u16* __restrict__ w2t, const float* __restrict__ g2,
            float* __restrict__ ext,
            float* __restrict__ psum, float* __restrict__ psumsq) {
    __shared__ __align__(16) u16 As[128 * 64];   // 16 KB
    __shared__ __align__(16) u16 Ws[256 * 64];   // 32 KB
    const int tid = threadIdx.x;
    const int bid = blockIdx.x;
    const int wave = tid >> 6, lane = tid & 63;
    const int wm = wave >> 1, wn = wave & 1;
    const int quad = lane >> 4, l16 = lane & 15;
    const int lrow = lane >> 3, lchk = lane & 7;
    const int gchk = lchk ^ lrow;
    const int sj = tid >> 3, sc8 = tid & 7;
    const int mt = bid >> 2, cs = bid & 3;       // consecutive bids: same M-tile
    const int s2 = mt >> 3, rb = mt & 7;
    const int pedb = rb << 2;
    const int N0 = cs << 8;
    const float* Aj = A + ((size_t)(s2 * 32 + sj) << 9) + (sc8 << 3);
    const float* Bp = Bv + ((size_t)(s2 * 32 + pedb) << 9) + (sc8 << 3);
    const int swz = (sc8 ^ (sj & 7)) << 3;

    floatx4 acc[4][8] = {};
    for (int it = 0; it < 8; ++it) {
        const int k0 = it << 6;
        // stage Ws: 256 rows x 64 k via global_load_lds
#pragma unroll
        for (int t = 0; t < 8; ++t) {
            const int rbase = (wave << 6) + (t << 3);
            const u16* gb = w2t + (size_t)(N0 + rbase + lrow) * 512 + (k0 + (gchk << 3));
            __builtin_amdgcn_global_load_lds(
                (const __attribute__((address_space(1))) void*)gb,
                (__attribute__((address_space(3))) void*)(Ws + (rbase << 6)), 16, 0, 0);
        }
        // stage As: 128 rows (4 peds x 32 j) x 64 k, per-lane relu-diff.
        {
            const float4 alo = *(const float4*)(Aj + k0);
            const float4 ahi = *(const float4*)(Aj + k0 + 4);
#pragma unroll
            for (int p = 0; p < 4; ++p) {
                const int r = (p << 5) + sj;
                const float4 blo = *(const float4*)(Bp + ((size_t)p << 9) + k0);
                const float4 bhi = *(const float4*)(Bp + ((size_t)p << 9) + k0 + 4);
                bf16x8 o;
                o[0] = (__bf16)fmaxf(alo.x - blo.x, 0.f);
                o[1] = (__bf16)fmaxf(alo.y - blo.y, 0.f);
                o[2] = (__bf16)fmaxf(alo.z - blo.z, 0.f);
                o[3] = (__bf16)fmaxf(alo.w - blo.w, 0.f);
                o[4] = (__bf16)fmaxf(ahi.x - bhi.x, 0.f);
                o[5] = (__bf16)fmaxf(ahi.y - bhi.y, 0.f);
                o[6] = (__bf16)fmaxf(ahi.z - bhi.z, 0.f);
                o[7] = (__bf16)fmaxf(ahi.w - bhi.w, 0.f);
                *(bf16x8*)(As + (r << 6) + swz) = o;
            }
        }
        __syncthreads();
#pragma unroll
        for (int kk = 0; kk < 2; ++kk) {
            const int ck = (kk << 2) + quad;
            const int po = (ck ^ (l16 & 7)) << 3;
            bf16x8 af[4], wf[8];
#pragma unroll
            for (int tm = 0; tm < 4; ++tm) {
                const int row = (wm << 6) + (tm << 4) + l16;
                af[tm] = *(const bf16x8*)(As + (row << 6) + po);
            }
#pragma unroll
            for (int tn = 0; tn < 8; ++tn) {
                const int wrow = (wn << 7) + (tn << 4) + l16;
                wf[tn] = *(const bf16x8*)(Ws + (wrow << 6) + ((ck ^ (wrow & 7)) << 3));
            }
#pragma unroll
            for (int tm = 0; tm < 4; ++tm)
#pragma unroll
                for (int tn = 0; tn < 8; ++tn)
                    acc[tm][tn] = __builtin_amdgcn_mfma_f32_16x16x32_bf16(
                        af[tm], wf[tn], acc[tm][tn], 0, 0, 0);
        }
        __syncthreads();
    }
    // epilogue: single j-extreme per ped (sign(g2)-selected) + BN2 partials
#pragma unroll
    for (int tn = 0; tn < 8; ++tn) {
        const int col = N0 + (wn << 7) + (tn << 4) + l16;
        const float g2v = g2[col];
        float wsum = 0.f, wsq = 0.f;
#pragma unroll
        for (int gp = 0; gp < 2; ++gp) {
            float vmax = -3.4e38f, vmin = 3.4e38f, vs = 0.f, vq = 0.f;
#pragma unroll
            for (int tm = gp * 2; tm < gp * 2 + 2; ++tm)
#pragma unroll
                for (int r = 0; r < 4; ++r) {
                    const float v = acc[tm][tn][r];
                    vmax = fmaxf(vmax, v);
                    vmin = fminf(vmin, v);
                    vs += v;
                    vq += v * v;
                }
#pragma unroll
            for (int off = 16; off < 64; off <<= 1) {
                vmax = fmaxf(vmax, __shfl_xor(vmax, off));
                vmin = fminf(vmin, __shfl_xor(vmin, off));
                vs += __shfl_xor(vs, off);
                vq += __shfl_xor(vq, off);
            }
            if (quad == 0) {
                const int kg = s2 * 32 + pedb + (wm << 1) + gp;
                ext[(size_t)kg * 1024 + col] = (g2v >= 0.f) ? vmax : vmin;
            }
            wsum += vs;
            wsq += vq;
        }
        if (quad == 0) {
            const int slot = (s2 << 4) + (rb << 1) + wm;  // 16 per scene
            psum[(size_t)slot * 1024 + col] = wsum;
            psumsq[(size_t)slot * 1024 + col] = wsq;
        }
    }
}

// ============================================================================
// Prep / final kernels
// ============================================================================
__global__ __launch_bounds__(256)
void k_prep(const float* __restrict__ pos, const float* __restrict__ h,
            const float* __restrict__ We, const float* __restrict__ W1,
            const float* __restrict__ g1, const float* __restrict__ be1,
            const float* __restrict__ W2,
            float* __restrict__ A, float* __restrict__ Bv, u16* __restrict__ w2t) {
    __shared__ __align__(16) char smem_raw[16912];
    const int bid = blockIdx.x;
    if (bid < 256)
        prep_scene_256(bid, threadIdx.x, (float*)smem_raw, pos, h, We, W1, g1, be1, A, Bv);
    else
        w2t_tile_256(bid - 256, threadIdx.x, smem_raw, W2, w2t);
}

__global__ __launch_bounds__(256)
void k_final(const float* __restrict__ ext,
             const float* __restrict__ psum, const float* __restrict__ psumsq,
             const float* __restrict__ g2, const float* __restrict__ be2,
             float* __restrict__ out) {
    const int u = blockIdx.x, tid = threadIdx.x;
    const int s3 = u >> 2;
    const int c = ((u & 3) << 8) + tid;
    float sm = 0.f, sq = 0.f;
#pragma unroll
    for (int t = 0; t < 16; ++t) {
        sm += psum[(size_t)(s3 * 16 + t) * 1024 + c];
        sq += psumsq[(size_t)(s3 * 16 + t) * 1024 + c];
    }
    const float mu = sm * (1.f / 1024.f);
    const float var = sq * (1.f / 1024.f) - mu * mu;
    const float inv = rsqrtf(var + EPS_);
    const float scale = g2[c] * inv;
    const float bb = be2[c];
    for (int k = 0; k < 32; ++k) {
        const float v = ext[(size_t)(s3 * 32 + k) * 1024 + c];
        out[(size_t)(s3 * 32 + k) * 1024 + c] = fmaxf((v - mu) * scale + bb, 0.f);
    }
}

extern "C" void kernel_launch(void* const* d_in, const int* in_sizes, int n_in,
                              void* d_out, int out_size, void* d_ws, size_t ws_size,
                              hipStream_t stream) {
    const float* h_states = (const float*)d_in[0];
    const float* end_pos = (const float*)d_in[2];
    const float* W_embed = (const float*)d_in[4];
    const float* W1 = (const float*)d_in[6];
    const float* g1 = (const float*)d_in[8];
    const float* be1 = (const float*)d_in[9];
    const float* W2 = (const float*)d_in[10];
    const float* g2 = (const float*)d_in[12];
    const float* be2 = (const float*)d_in[13];
    float* out = (float*)d_out;

    float* Abuf = (float*)d_ws;                // 1,048,576 f
    float* Bbuf = Abuf + 1048576;              // 1,048,576 f
    float* ext = Bbuf + 1048576;               // 2,097,152 f
    float* psum = ext + 2097152;               // 1,048,576 f
    float* psumsq = psum + 1048576;            // 1,048,576 f
    u16* w2t = (u16*)(psumsq + 1048576);       // 524,288 u16

    k_prep<<<dim3(384), dim3(256), 0, stream>>>(end_pos, h_states, W_embed, W1,
                                                g1, be1, W2, Abuf, Bbuf, w2t);
    k_gemm<<<dim3(2048), dim3(256), 0, stream>>>(Abuf, Bbuf, w2t, g2,
                                                 ext, psum, psumsq);
    k_final<<<dim3(256), dim3(256), 0, stream>>>(ext, psum, psumsq, g2, be2, out);
}

// Round 18
// 180.481 us; speedup vs baseline: 1.2800x; 1.0092x over previous
//
#include <hip/hip_runtime.h>
#include <hip/hip_bf16.h>

#define S_ 64
#define P_ 32
#define N_ 2048
#define H_ 64
#define E_ 64
#define D1_ 512
#define D2_ 1024
#define EPS_ 1e-5f

typedef unsigned short u16;
using bf16x8 = __attribute__((ext_vector_type(8))) __bf16;
using floatx4 = __attribute__((ext_vector_type(4))) float;

__device__ inline u16 f2bf(float x) {
    unsigned u = __float_as_uint(x);
    unsigned r = (u + 0x7fffu + ((u >> 16) & 1u)) >> 16;
    return (u16)r;
}

// ============================================================================
// Device helpers (logic verified on HW across this + prior session)
// ============================================================================

// Scene prep for one (scene, d-quarter), 256 threads. Writes BN1'd A/B factors.
__device__ void prep_scene_256(int u, int tid, float* smem,
                               const float* __restrict__ pos, const float* __restrict__ h,
                               const float* __restrict__ We, const float* __restrict__ W1,
                               const float* __restrict__ g1, const float* __restrict__ be1,
                               float* __restrict__ A, float* __restrict__ Bv) {
    const int s = u >> 2, dq = u & 3;
    const int jg = tid >> 7, dl = tid & 127;   // 2 j-groups x 128 channels
    const int d = (dq << 7) + dl;
    float* hs = smem;           // 2048: h[j][e]
    float* ps = smem + 2048;    // 64: pos
    float* red = smem + 2112;   // 1024: 4 stats x 256 threads
    for (int i = tid; i < 2048; i += 256) hs[i] = h[(size_t)s * 2048 + i];
    if (tid < 64) ps[tid] = pos[s * 64 + tid];
    __syncthreads();
    float wq0 = 0.f, wq1 = 0.f;
    for (int e = 0; e < 64; ++e) {
        const float wv = W1[e * 512 + d];
        wq0 += We[e] * wv;
        wq1 += We[64 + e] * wv;
    }
    float w[16], uu[16];
#pragma unroll
    for (int jj = 0; jj < 16; ++jj) w[jj] = 0.f;
    const float4* h4 = (const float4*)hs;
    for (int e4 = 0; e4 < 16; ++e4) {
        const float c0 = W1[(64 + e4 * 4 + 0) * 512 + d];
        const float c1 = W1[(64 + e4 * 4 + 1) * 512 + d];
        const float c2 = W1[(64 + e4 * 4 + 2) * 512 + d];
        const float c3 = W1[(64 + e4 * 4 + 3) * 512 + d];
#pragma unroll
        for (int jj = 0; jj < 16; ++jj) {
            const float4 hv = h4[((jg << 4) + jj) * 16 + e4];
            w[jj] += hv.x * c0 + hv.y * c1 + hv.z * c2 + hv.w * c3;
        }
    }
    float sw = 0.f, sww = 0.f, su = 0.f, suu = 0.f;
#pragma unroll
    for (int jj = 0; jj < 16; ++jj) {
        const int j = (jg << 4) + jj;
        uu[jj] = ps[2 * j] * wq0 + ps[2 * j + 1] * wq1;
        w[jj] += uu[jj];
        sw += w[jj]; sww += w[jj] * w[jj];
        su += uu[jj]; suu += uu[jj] * uu[jj];
    }
    red[(jg << 7) + dl] = sw;
    red[256 + (jg << 7) + dl] = sww;
    red[512 + (jg << 7) + dl] = su;
    red[768 + (jg << 7) + dl] = suu;
    __syncthreads();
    const float tw = red[dl] + red[128 + dl];
    const float tww = red[256 + dl] + red[384 + dl];
    const float tu = red[512 + dl] + red[640 + dl];
    const float tuu = red[768 + dl] + red[896 + dl];
    const float mw = tw * (1.f / 32.f), mu2 = tu * (1.f / 32.f);
    const float var = (tww * (1.f / 32.f) - mw * mw) + (tuu * (1.f / 32.f) - mu2 * mu2);
    const float sc = rsqrtf(var + EPS_) * g1[d];
    const float bb = be1[d];
#pragma unroll
    for (int jj = 0; jj < 16; ++jj) {
        const int j = (jg << 4) + jj;
        A[(size_t)(s * 32 + j) * 512 + d] = (w[jj] - mw) * sc + bb;
        Bv[(size_t)(s * 32 + j) * 512 + d] = (uu[jj] - mu2) * sc;
    }
}

// W2 transpose+bf16 for one 64x64 tile, 256 threads.
__device__ void w2t_tile_256(int b2, int tid, void* smem,
                             const float* __restrict__ W2, u16* __restrict__ w2t) {
    float (*tile)[65] = (float (*)[65])smem;  // 16.6 KB
    const int bi = b2 & 15, bj = b2 >> 4;     // 16 n-tiles x 8 k-tiles
    const int tx = tid & 63, ty = tid >> 6;   // 64 x 4
#pragma unroll
    for (int i = 0; i < 64; i += 4)
        tile[ty + i][tx] = W2[(size_t)(bj * 64 + ty + i) * 1024 + bi * 64 + tx];
    __syncthreads();
#pragma unroll
    for (int i = 0; i < 64; i += 4)
        w2t[(size_t)(bi * 64 + ty + i) * 512 + bj * 64 + tx] = f2bf(tile[tx][ty + i]);
}

// ============================================================================
// Fused GEMM — r13 byte-exact (session best-measured: 91.1 us, total 180.9):
// r8's proven loop (48 KB static LDS, 2-3 blocks/CU independent barrier
// domains, block = (M-tile 128 rows, 256-col split), grid 2048 with
// consecutive bids sharing the M-tile for L2 reuse, wave-tile 64x128
// af[4]/wf[8] = 2.67 MFMA/read, single-buffered Ws via global_load_lds,
// __syncthreads drains, R5 swizzles, 0 bank conflicts)
// + entry s_sleep stagger on odd blocks (r13 vs r17 clean pair: 91.1 vs 98.3
//   — either real de-phasing of co-resident blocks' barrier drains, or
//   container noise; keeping the measured-best variant costs nothing)
// + single j-extreme epilogue keyed on sign(g2) (verified; WRITE 24.6->16.4).
// Falsified levers (do not revisit): 4/2-phase 256-sq pipelines, counted
// vmcnt at 48/80/96 KB, 1-block full dbuf, >=3-block TLP, setprio, per-block
// fences, cooperative fusion, BN2-closure-in-block. Deep pipelines cannot
// amortize at K=512 (8 K-tiles: ~3/8 fill/drain). MX-fp8 closed by numerics.
// ============================================================================
__global__ __launch_bounds__(256, 2)
void k_gemm(const float* __restrict__ A, const float* __restrict__ Bv,
            const u16* __restrict__ w2t, const float* __restrict__ g2,
            float* __restrict__ ext,
            float* __restrict__ psum, float* __restrict__ psumsq) {
    __shared__ __align__(16) u16 As[128 * 64];   // 16 KB
    __shared__ __align__(16) u16 Ws[256 * 64];   // 32 KB
    const int tid = threadIdx.x;
    const int bid = blockIdx.x;
    // de-align co-resident blocks: ~27*64 = 1728 cyc one-time skew
    if (bid & 1) {
        __builtin_amdgcn_s_sleep(27);
    }
    const int wave = tid >> 6, lane = tid & 63;
    const int wm = wave >> 1, wn = wave & 1;
    const int quad = lane >> 4, l16 = lane & 15;
    const int lrow = lane >> 3, lchk = lane & 7;
    const int gchk = lchk ^ lrow;
    const int sj = tid >> 3, sc8 = tid & 7;
    const int mt = bid >> 2, cs = bid & 3;       // consecutive bids: same M-tile
    const int s2 = mt >> 3, rb = mt & 7;
    const int pedb = rb << 2;
    const int N0 = cs << 8;
    const float* Aj = A + ((size_t)(s2 * 32 + sj) << 9) + (sc8 << 3);
    const float* Bp = Bv + ((size_t)(s2 * 32 + pedb) << 9) + (sc8 << 3);
    const int swz = (sc8 ^ (sj & 7)) << 3;

    floatx4 acc[4][8] = {};
    for (int it = 0; it < 8; ++it) {
        const int k0 = it << 6;
        // stage Ws: 256 rows x 64 k via global_load_lds
#pragma unroll
        for (int t = 0; t < 8; ++t) {
            const int rbase = (wave << 6) + (t << 3);
            const u16* gb = w2t + (size_t)(N0 + rbase + lrow) * 512 + (k0 + (gchk << 3));
            __builtin_amdgcn_global_load_lds(
                (const __attribute__((address_space(1))) void*)gb,
                (__attribute__((address_space(3))) void*)(Ws + (rbase << 6)), 16, 0, 0);
        }
        // stage As: 128 rows (4 peds x 32 j) x 64 k, per-lane relu-diff.
        {
            const float4 alo = *(const float4*)(Aj + k0);
            const float4 ahi = *(const float4*)(Aj + k0 + 4);
#pragma unroll
            for (int p = 0; p < 4; ++p) {
                const int r = (p << 5) + sj;
                const float4 blo = *(const float4*)(Bp + ((size_t)p << 9) + k0);
                const float4 bhi = *(const float4*)(Bp + ((size_t)p << 9) + k0 + 4);
                bf16x8 o;
                o[0] = (__bf16)fmaxf(alo.x - blo.x, 0.f);
                o[1] = (__bf16)fmaxf(alo.y - blo.y, 0.f);
                o[2] = (__bf16)fmaxf(alo.z - blo.z, 0.f);
                o[3] = (__bf16)fmaxf(alo.w - blo.w, 0.f);
                o[4] = (__bf16)fmaxf(ahi.x - bhi.x, 0.f);
                o[5] = (__bf16)fmaxf(ahi.y - bhi.y, 0.f);
                o[6] = (__bf16)fmaxf(ahi.z - bhi.z, 0.f);
                o[7] = (__bf16)fmaxf(ahi.w - bhi.w, 0.f);
                *(bf16x8*)(As + (r << 6) + swz) = o;
            }
        }
        __syncthreads();
#pragma unroll
        for (int kk = 0; kk < 2; ++kk) {
            const int ck = (kk << 2) + quad;
            const int po = (ck ^ (l16 & 7)) << 3;
            bf16x8 af[4], wf[8];
#pragma unroll
            for (int tm = 0; tm < 4; ++tm) {
                const int row = (wm << 6) + (tm << 4) + l16;
                af[tm] = *(const bf16x8*)(As + (row << 6) + po);
            }
#pragma unroll
            for (int tn = 0; tn < 8; ++tn) {
                const int wrow = (wn << 7) + (tn << 4) + l16;
                wf[tn] = *(const bf16x8*)(Ws + (wrow << 6) + ((ck ^ (wrow & 7)) << 3));
            }
#pragma unroll
            for (int tm = 0; tm < 4; ++tm)
#pragma unroll
                for (int tn = 0; tn < 8; ++tn)
                    acc[tm][tn] = __builtin_amdgcn_mfma_f32_16x16x32_bf16(
                        af[tm], wf[tn], acc[tm][tn], 0, 0, 0);
        }
        __syncthreads();
    }
    // epilogue: single j-extreme per ped (sign(g2)-selected) + BN2 partials
#pragma unroll
    for (int tn = 0; tn < 8; ++tn) {
        const int col = N0 + (wn << 7) + (tn << 4) + l16;
        const float g2v = g2[col];
        float wsum = 0.f, wsq = 0.f;
#pragma unroll
        for (int gp = 0; gp < 2; ++gp) {
            float vmax = -3.4e38f, vmin = 3.4e38f, vs = 0.f, vq = 0.f;
#pragma unroll
            for (int tm = gp * 2; tm < gp * 2 + 2; ++tm)
#pragma unroll
                for (int r = 0; r < 4; ++r) {
                    const float v = acc[tm][tn][r];
                    vmax = fmaxf(vmax, v);
                    vmin = fminf(vmin, v);
                    vs += v;
                    vq += v * v;
                }
#pragma unroll
            for (int off = 16; off < 64; off <<= 1) {
                vmax = fmaxf(vmax, __shfl_xor(vmax, off));
                vmin = fminf(vmin, __shfl_xor(vmin, off));
                vs += __shfl_xor(vs, off);
                vq += __shfl_xor(vq, off);
            }
            if (quad == 0) {
                const int kg = s2 * 32 + pedb + (wm << 1) + gp;
                ext[(size_t)kg * 1024 + col] = (g2v >= 0.f) ? vmax : vmin;
            }
            wsum += vs;
            wsq += vq;
        }
        if (quad == 0) {
            const int slot = (s2 << 4) + (rb << 1) + wm;  // 16 per scene
            psum[(size_t)slot * 1024 + col] = wsum;
            psumsq[(size_t)slot * 1024 + col] = wsq;
        }
    }
}

// ============================================================================
// Prep / final kernels
// ============================================================================
__global__ __launch_bounds__(256)
void k_prep(const float* __restrict__ pos, const float* __restrict__ h,
            const float* __restrict__ We, const float* __restrict__ W1,
            const float* __restrict__ g1, const float* __restrict__ be1,
            const float* __restrict__ W2,
            float* __restrict__ A, float* __restrict__ Bv, u16* __restrict__ w2t) {
    __shared__ __align__(16) char smem_raw[16912];
    const int bid = blockIdx.x;
    if (bid < 256)
        prep_scene_256(bid, threadIdx.x, (float*)smem_raw, pos, h, We, W1, g1, be1, A, Bv);
    else
        w2t_tile_256(bid - 256, threadIdx.x, smem_raw, W2, w2t);
}

__global__ __launch_bounds__(256)
void k_final(const float* __restrict__ ext,
             const float* __restrict__ psum, const float* __restrict__ psumsq,
             const float* __restrict__ g2, const float* __restrict__ be2,
             float* __restrict__ out) {
    const int u = blockIdx.x, tid = threadIdx.x;
    const int s3 = u >> 2;
    const int c = ((u & 3) << 8) + tid;
    float sm = 0.f, sq = 0.f;
#pragma unroll
    for (int t = 0; t < 16; ++t) {
        sm += psum[(size_t)(s3 * 16 + t) * 1024 + c];
        sq += psumsq[(size_t)(s3 * 16 + t) * 1024 + c];
    }
    const float mu = sm * (1.f / 1024.f);
    const float var = sq * (1.f / 1024.f) - mu * mu;
    const float inv = rsqrtf(var + EPS_);
    const float scale = g2[c] * inv;
    const float bb = be2[c];
    for (int k = 0; k < 32; ++k) {
        const float v = ext[(size_t)(s3 * 32 + k) * 1024 + c];
        out[(size_t)(s3 * 32 + k) * 1024 + c] = fmaxf((v - mu) * scale + bb, 0.f);
    }
}

extern "C" void kernel_launch(void* const* d_in, const int* in_sizes, int n_in,
                              void* d_out, int out_size, void* d_ws, size_t ws_size,
                              hipStream_t stream) {
    const float* h_states = (const float*)d_in[0];
    const float* end_pos = (const float*)d_in[2];
    const float* W_embed = (const float*)d_in[4];
    const float* W1 = (const float*)d_in[6];
    const float* g1 = (const float*)d_in[8];
    const float* be1 = (const float*)d_in[9];
    const float* W2 = (const float*)d_in[10];
    const float* g2 = (const float*)d_in[12];
    const float* be2 = (const float*)d_in[13];
    float* out = (float*)d_out;

    float* Abuf = (float*)d_ws;                // 1,048,576 f
    float* Bbuf = Abuf + 1048576;              // 1,048,576 f
    float* ext = Bbuf + 1048576;               // 2,097,152 f
    float* psum = ext + 2097152;               // 1,048,576 f
    float* psumsq = psum + 1048576;            // 1,048,576 f
    u16* w2t = (u16*)(psumsq + 1048576);       // 524,288 u16

    k_prep<<<dim3(384), dim3(256), 0, stream>>>(end_pos, h_states, W_embed, W1,
                                                g1, be1, W2, Abuf, Bbuf, w2t);
    k_gemm<<<dim3(2048), dim3(256), 0, stream>>>(Abuf, Bbuf, w2t, g2,
                                                 ext, psum, psumsq);
    k_final<<<dim3(256), dim3(256), 0, stream>>>(ext, psum, psumsq, g2, be2, out);
}